// Round 5
// baseline (298.427 us; speedup 1.0000x reference)
//
#include <hip/hip_runtime.h>

#define DD 160

// ============ K1: X-pass (templated) ============
// in/tg raw [B][160][160][160] -> xb 5 channels [ch][b][x'][y][z].
// Thread = (chunk, chain, b, y, z); slides window along x.
// NCH parity chains (2 for odd S); slide step NCH*S even -> remove/add R taps.
template<int N, int K, int S, int NCH, int CL>
__global__ __launch_bounds__(256) void k1t(
    const float* __restrict__ in, const float* __restrict__ tg,
    float* __restrict__ xb, int B) {
    const long XS = (long)DD * DD;
    const long P  = (long)B * XS;
    constexpr int NPC0 = (N + NCH - 1) / NCH;
    constexpr int CC   = (NPC0 + CL - 1) / CL;
    constexpr int R    = (NCH * S) / 2;
    long t = (long)blockIdx.x * 256 + threadIdx.x;
    if (t >= P * NCH * CC) return;
    long p = t % P;
    int  r = (int)(t / P);
    int chain  = r % NCH;
    int cchunk = r / NCH;
    int b = (int)(p / XS);
    long yz = p % XS;
    const float* ia = in + (long)b * DD * XS + yz;
    const float* ta = tg + (long)b * DD * XS + yz;
    const long CH = (long)B * N * XS;
    float* ob = xb + (long)b * N * XS + yz;

    const int npc = (N - chain + NCH - 1) / NCH;
    int j0 = cchunk * CL;
    if (j0 >= npc) return;
    int xp = chain + j0 * NCH;
    int x0 = xp * S;
    float s0 = 0.f, s1 = 0.f, s2 = 0.f, s3 = 0.f, s4 = 0.f;
#pragma unroll
    for (int i = 0; i < K; ++i) {
        float a = ia[(long)(x0 + 2 * i) * XS];
        float c = ta[(long)(x0 + 2 * i) * XS];
        s0 += a; s1 += c; s2 += a * a; s3 += c * c; s4 += a * c;
    }
    {
        long oo = (long)xp * XS;
        ob[oo] = s0; ob[oo + CH] = s1; ob[oo + 2 * CH] = s2;
        ob[oo + 3 * CH] = s3; ob[oo + 4 * CH] = s4;
    }
#pragma unroll
    for (int q = 1; q < CL; ++q) {
        if (j0 + q >= npc) break;
#pragma unroll
        for (int j = 0; j < R; ++j) {
            float a = ia[(long)(x0 + 2 * j) * XS];
            float c = ta[(long)(x0 + 2 * j) * XS];
            s0 -= a; s1 -= c; s2 -= a * a; s3 -= c * c; s4 -= a * c;
            a = ia[(long)(x0 + 2 * K + 2 * j) * XS];
            c = ta[(long)(x0 + 2 * K + 2 * j) * XS];
            s0 += a; s1 += c; s2 += a * a; s3 += c * c; s4 += a * c;
        }
        xp += NCH;
        x0 += NCH * S;
        long oo = (long)xp * XS;
        ob[oo] = s0; ob[oo + CH] = s1; ob[oo + 2 * CH] = s2;
        ob[oo + 3 * CH] = s3; ob[oo + 4 * CH] = s4;
    }
}

// ============ K23: fused Y-window + Z-scan + LNCC + reduction ============
// One wave per output row (b,x',y'): per channel, sum K y-tap columns of xb
// (each 160 contiguous floats) into a z-vector in regs, parity prefix-scan
// along z, window-diff -> LNCC -> block reduce -> atomic.
template<int N, int K, int S>
__global__ __launch_bounds__(256) void k23t(
    const float* __restrict__ xb, float* __restrict__ acc, int B) {
    constexpr float numel = (float)K * K * K;
    __shared__ float Sm[4][5][162];
    __shared__ float wsum[4];
    const int wid = threadIdx.x >> 6, lane = threadIdx.x & 63;
    const long XS = (long)DD * DD;
    const long CH = (long)B * N * XS;
    const long R3 = (long)B * N * N;
    const long row = (long)blockIdx.x * 4 + wid;
    float v = 0.f;
    if (row < R3) {
        int yp = (int)(row % N); long rr = row / N;
        int xp = (int)(rr % N);
        int b  = (int)(rr / N);
        const float* base = xb + ((long)b * N + xp) * XS + (long)(yp * S) * DD;
        float* Sw = &Sm[wid][0][0];
#pragma unroll
        for (int ch = 0; ch < 5; ++ch) {
            const float* cp = base + (long)ch * CH;
            float v0 = 0.f, v1 = 0.f, v2 = 0.f;
#pragma unroll
            for (int i = 0; i < K; ++i) {
                const float* pp = cp + (long)(2 * i) * DD;
                v0 += pp[lane];
                v1 += pp[lane + 64];
                if (lane < 32) v2 += pp[lane + 128];
            }
#pragma unroll
            for (int o = 2; o <= 32; o <<= 1) {
                float t0 = __shfl_up(v0, o);
                float t1 = __shfl_up(v1, o);
                float t2 = __shfl_up(v2, o);
                if (lane >= o) { v0 += t0; v1 += t1; v2 += t2; }
            }
            float c1 = __shfl(v0, 62 + (lane & 1)); v1 += c1;
            float c2 = __shfl(v1, 62 + (lane & 1)); v2 += c2;
            float* outp = Sw + ch * 162;
            if (lane < 2) outp[lane] = 0.f;
            outp[lane + 2]  = v0;
            outp[lane + 66] = v1;
            if (lane < 32) outp[lane + 130] = v2;
        }
#pragma unroll
        for (int t = lane; t < N; t += 64) {
            int lo = t * S, hi = lo + 2 * K;
            float a0 = Sw[0 * 162 + hi] - Sw[0 * 162 + lo];
            float a1 = Sw[1 * 162 + hi] - Sw[1 * 162 + lo];
            float a2 = Sw[2 * 162 + hi] - Sw[2 * 162 + lo];
            float a3 = Sw[3 * 162 + hi] - Sw[3 * 162 + lo];
            float a4 = Sw[4 * 162 + hi] - Sw[4 * 162 + lo];
            float xm = a0 / numel, ym = a1 / numel;
            float cross = a4 - ym * a0 - xm * a1 + ym * xm * numel;
            float xvar  = a2 - 2.f * xm * a0 + xm * xm * numel;
            float yvar  = a3 - 2.f * ym * a1 + ym * ym * numel;
            v += cross * cross / (xvar * yvar + 1e-5f);
        }
    }
    for (int o = 32; o > 0; o >>= 1) v += __shfl_down(v, o, 64);
    if (lane == 0) wsum[wid] = v;
    __syncthreads();
    if (threadIdx.x == 0) atomicAdd(acc, wsum[0] + wsum[1] + wsum[2] + wsum[3]);
}

__global__ void finalize_kernel(const float* __restrict__ acc, float* __restrict__ out,
                                float c0, float c1, float c2,
                                float w0, float w1, float w2) {
    if (threadIdx.x == 0 && blockIdx.x == 0) {
        out[0] = w0 * (1.f - acc[0] / c0) +
                 w1 * (1.f - acc[1] / c1) +
                 w2 * (1.f - acc[2] / c2);
    }
}

// ---- per-scale launcher ----
template<int N, int K, int S, int NCH, int CL1>
static void run_scale(const float* ip, const float* tp, float* xb,
                      float* acc, int B, hipStream_t stream) {
    constexpr int NPC0 = (N + NCH - 1) / NCH;
    constexpr int CC1  = (NPC0 + CL1 - 1) / CL1;
    const long P  = (long)B * DD * DD;
    const long t1 = P * NCH * CC1;
    k1t<N, K, S, NCH, CL1><<<dim3((unsigned)((t1 + 255) / 256)), dim3(256), 0, stream>>>(
        ip, tp, xb, B);
    const long R3 = (long)B * N * N;
    k23t<N, K, S><<<dim3((unsigned)((R3 + 3) / 4)), dim3(256), 0, stream>>>(xb, acc, B);
}

extern "C" void kernel_launch(void* const* d_in, const int* in_sizes, int n_in,
                              void* d_out, int out_size, void* d_ws, size_t ws_size,
                              hipStream_t stream) {
    const float* input  = (const float*)d_in[0];
    const float* target = (const float*)d_in[1];
    float* out = (float*)d_out;

    char* ws = (char*)d_ws;
    float* acc = (float*)ws;
    const size_t accPad = 256;

    const size_t xbF = 5ull * 2 * 71 * DD * DD;                    // scale-0 max
    const size_t fullNeed = accPad + xbF * sizeof(float);          // ~72.7 MB
    const int NB = (ws_size >= fullNeed) ? 2 : 1;

    float* xb = (float*)(ws + accPad);

    hipMemsetAsync(acc, 0, 3 * sizeof(float), stream);

    for (int b0 = 0; b0 < 2; b0 += NB) {
        const float* ip = input  + (size_t)b0 * DD * DD * DD;
        const float* tp = target + (size_t)b0 * DD * DD * DD;
        run_scale<71, 10,  2, 1, 12>(ip, tp, xb, acc + 0, NB, stream);
        run_scale<25, 20,  5, 2,  7>(ip, tp, xb, acc + 1, NB, stream);
        run_scale< 9, 40, 10, 1,  5>(ip, tp, xb, acc + 2, NB, stream);
    }
    finalize_kernel<<<dim3(1), dim3(64), 0, stream>>>(
        acc, out,
        2.f * 71.f * 71.f * 71.f,
        2.f * 25.f * 25.f * 25.f,
        2.f * 9.f * 9.f * 9.f,
        0.1f, 0.3f, 0.6f);
}

// Round 6
// 297.176 us; speedup vs baseline: 1.0042x; 1.0042x over previous
//
#include <hip/hip_runtime.h>

#define DD 160

// ============ K1 body: x-pass sliding window (one scale) ============
// in/tg raw [B][160][160][160] -> xb 5 channels [ch][b][x'][y][z].
// NCH parity chains (2 for odd S); slide step NCH*S even -> remove/add R taps.
template<int N, int K, int S, int NCH, int CL>
__device__ __forceinline__ void k1_body(
    const float* __restrict__ in, const float* __restrict__ tg,
    float* __restrict__ xb, int B, long t) {
    const long XS = (long)DD * DD;
    const long P  = (long)B * XS;
    constexpr int NPC0 = (N + NCH - 1) / NCH;
    constexpr int CC   = (NPC0 + CL - 1) / CL;
    constexpr int R    = (NCH * S) / 2;
    if (t >= P * NCH * CC) return;
    long p = t % P;
    int  r = (int)(t / P);
    int chain  = r % NCH;
    int cchunk = r / NCH;
    int b = (int)(p / XS);
    long yz = p % XS;
    const float* ia = in + (long)b * DD * XS + yz;
    const float* ta = tg + (long)b * DD * XS + yz;
    const long CH = (long)B * N * XS;
    float* ob = xb + (long)b * N * XS + yz;

    const int npc = (N - chain + NCH - 1) / NCH;
    int j0 = cchunk * CL;
    if (j0 >= npc) return;
    int xp = chain + j0 * NCH;
    int x0 = xp * S;
    float s0 = 0.f, s1 = 0.f, s2 = 0.f, s3 = 0.f, s4 = 0.f;
#pragma unroll
    for (int i = 0; i < K; ++i) {
        float a = ia[(long)(x0 + 2 * i) * XS];
        float c = ta[(long)(x0 + 2 * i) * XS];
        s0 += a; s1 += c; s2 += a * a; s3 += c * c; s4 += a * c;
    }
    {
        long oo = (long)xp * XS;
        ob[oo] = s0; ob[oo + CH] = s1; ob[oo + 2 * CH] = s2;
        ob[oo + 3 * CH] = s3; ob[oo + 4 * CH] = s4;
    }
#pragma unroll
    for (int q = 1; q < CL; ++q) {
        if (j0 + q >= npc) break;
#pragma unroll
        for (int j = 0; j < R; ++j) {
            float a = ia[(long)(x0 + 2 * j) * XS];
            float c = ta[(long)(x0 + 2 * j) * XS];
            s0 -= a; s1 -= c; s2 -= a * a; s3 -= c * c; s4 -= a * c;
            a = ia[(long)(x0 + 2 * K + 2 * j) * XS];
            c = ta[(long)(x0 + 2 * K + 2 * j) * XS];
            s0 += a; s1 += c; s2 += a * a; s3 += c * c; s4 += a * c;
        }
        xp += NCH;
        x0 += NCH * S;
        long oo = (long)xp * XS;
        ob[oo] = s0; ob[oo + CH] = s1; ob[oo + 2 * CH] = s2;
        ob[oo + 3 * CH] = s3; ob[oo + 4 * CH] = s4;
    }
}

// All three scales in one dispatch (block-range segmented).
__global__ __launch_bounds__(256) void k1all(
    const float* __restrict__ in, const float* __restrict__ tg,
    float* __restrict__ xb0, float* __restrict__ xb1, float* __restrict__ xb2,
    int B, int nb0, int nb1) {
    int bid = blockIdx.x;
    if (bid < nb0) {
        long t = (long)bid * 256 + threadIdx.x;
        k1_body<71, 10, 2, 1, 12>(in, tg, xb0, B, t);
    } else if (bid < nb0 + nb1) {
        long t = (long)(bid - nb0) * 256 + threadIdx.x;
        k1_body<25, 20, 5, 2, 7>(in, tg, xb1, B, t);
    } else {
        long t = (long)(bid - nb0 - nb1) * 256 + threadIdx.x;
        k1_body<9, 40, 10, 1, 5>(in, tg, xb2, B, t);
    }
}

// ============ K23 body: fused y-window + z-scan + LNCC (one row per block) ====
// 4 waves cooperate on one output row (b,x',y'):
//   phase 1: tap-columns split across waves (i ≡ wid mod 4), per-channel reg
//            accumulation (ch = compile-time outer loop), partials -> LDS slab
//   phase 2: per-channel slab-reduce + parity prefix scan (channels over waves)
//   phase 3: window-diff -> LNCC on all 256 threads, block reduce, atomicAdd.
template<int N, int K, int S>
__device__ __forceinline__ void k23_body(
    const float* __restrict__ xb, float* __restrict__ acc, int B, int row,
    float (*Spart)[5][160], float (*Sm)[162], float* wsum) {
    constexpr float numel = (float)K * K * K;
    const int tid = threadIdx.x, wid = tid >> 6, lane = tid & 63;
    const long XS = (long)DD * DD;
    const long CH = (long)B * N * XS;
    int yp = row % N; int rr = row / N;
    int xp = rr % N;  int b  = rr / N;
    const float* base = xb + ((long)b * N + xp) * XS + (long)(yp * S) * DD;

#pragma unroll
    for (int ch = 0; ch < 5; ++ch) {
        const float* cp = base + (long)ch * CH;
        float v0 = 0.f, v1 = 0.f, v2 = 0.f;
#pragma unroll
        for (int j = 0; j < (K + 3) / 4; ++j) {
            int i = wid + 4 * j;
            if (i < K) {
                const float* pp = cp + (long)(2 * i) * DD;
                v0 += pp[lane];
                v1 += pp[lane + 64];
                if (lane < 32) v2 += pp[lane + 128];
            }
        }
        Spart[wid][ch][lane]      = v0;
        Spart[wid][ch][lane + 64] = v1;
        if (lane < 32) Spart[wid][ch][lane + 128] = v2;
    }
    __syncthreads();

    for (int ch = wid; ch < 5; ch += 4) {
        float v0 = Spart[0][ch][lane]       + Spart[1][ch][lane]
                 + Spart[2][ch][lane]       + Spart[3][ch][lane];
        float v1 = Spart[0][ch][lane + 64]  + Spart[1][ch][lane + 64]
                 + Spart[2][ch][lane + 64]  + Spart[3][ch][lane + 64];
        float v2 = 0.f;
        if (lane < 32)
            v2 = Spart[0][ch][lane + 128] + Spart[1][ch][lane + 128]
               + Spart[2][ch][lane + 128] + Spart[3][ch][lane + 128];
#pragma unroll
        for (int o = 2; o <= 32; o <<= 1) {
            float t0 = __shfl_up(v0, o);
            float t1 = __shfl_up(v1, o);
            float t2 = __shfl_up(v2, o);
            if (lane >= o) { v0 += t0; v1 += t1; v2 += t2; }
        }
        float c1 = __shfl(v0, 62 + (lane & 1)); v1 += c1;
        float c2 = __shfl(v1, 62 + (lane & 1)); v2 += c2;
        if (lane < 2) Sm[ch][lane] = 0.f;
        Sm[ch][lane + 2]  = v0;
        Sm[ch][lane + 66] = v1;
        if (lane < 32) Sm[ch][lane + 130] = v2;
    }
    __syncthreads();

    float v = 0.f;
    for (int t = tid; t < N; t += 256) {
        int lo = t * S, hi = lo + 2 * K;
        float a0 = Sm[0][hi] - Sm[0][lo];
        float a1 = Sm[1][hi] - Sm[1][lo];
        float a2 = Sm[2][hi] - Sm[2][lo];
        float a3 = Sm[3][hi] - Sm[3][lo];
        float a4 = Sm[4][hi] - Sm[4][lo];
        float xm = a0 / numel, ym = a1 / numel;
        float cross = a4 - ym * a0 - xm * a1 + ym * xm * numel;
        float xvar  = a2 - 2.f * xm * a0 + xm * xm * numel;
        float yvar  = a3 - 2.f * ym * a1 + ym * ym * numel;
        v += cross * cross / (xvar * yvar + 1e-5f);
    }
    for (int o = 32; o > 0; o >>= 1) v += __shfl_down(v, o, 64);
    if (lane == 0) wsum[wid] = v;
    __syncthreads();
    if (tid == 0) atomicAdd(acc, wsum[0] + wsum[1] + wsum[2] + wsum[3]);
}

// Segments ordered s2, s1, s0 so the few long-serial small-scale blocks
// dispatch first and hide under the s0 block ocean.
__global__ __launch_bounds__(256) void k23all(
    const float* __restrict__ xb0, const float* __restrict__ xb1,
    const float* __restrict__ xb2, float* __restrict__ acc,
    int B, int r2, int r1) {
    __shared__ float Spart[4][5][160];
    __shared__ float Sm[5][162];
    __shared__ float wsum[4];
    int bid = blockIdx.x;
    if (bid < r2)
        k23_body<9, 40, 10>(xb2, acc + 2, B, bid, Spart, Sm, wsum);
    else if (bid < r2 + r1)
        k23_body<25, 20, 5>(xb1, acc + 1, B, bid - r2, Spart, Sm, wsum);
    else
        k23_body<71, 10, 2>(xb0, acc + 0, B, bid - r2 - r1, Spart, Sm, wsum);
}

__global__ void finalize_kernel(const float* __restrict__ acc, float* __restrict__ out,
                                float c0, float c1, float c2,
                                float w0, float w1, float w2) {
    if (threadIdx.x == 0 && blockIdx.x == 0) {
        out[0] = w0 * (1.f - acc[0] / c0) +
                 w1 * (1.f - acc[1] / c1) +
                 w2 * (1.f - acc[2] / c2);
    }
}

extern "C" void kernel_launch(void* const* d_in, const int* in_sizes, int n_in,
                              void* d_out, int out_size, void* d_ws, size_t ws_size,
                              hipStream_t stream) {
    const float* input  = (const float*)d_in[0];
    const float* target = (const float*)d_in[1];
    float* out = (float*)d_out;

    char* ws = (char*)d_ws;
    float* acc = (float*)ws;
    const size_t accPad = 256;
    const long XS = (long)DD * DD;

    // full-batch (NB=2) need: 5*2*(71+25+9)*25600 floats = ~107.5 MB
    const size_t fullNeed = accPad + 5ull * 2 * 105 * XS * sizeof(float);
    const int NB = (ws_size >= fullNeed) ? 2 : 1;

    float* xb0 = (float*)(ws + accPad);
    float* xb1 = xb0 + 5ull * NB * 71 * XS;
    float* xb2 = xb1 + 5ull * NB * 25 * XS;

    hipMemsetAsync(acc, 0, 3 * sizeof(float), stream);

    for (int b0 = 0; b0 < 2; b0 += NB) {
        const float* ip = input  + (size_t)b0 * DD * XS;
        const float* tp = target + (size_t)b0 * DD * XS;
        // k1 blocks per scale: s0 600*B (CC=6), s1 400*B (NCH*CC=4), s2 200*B (CC=2)
        const int nb0 = 600 * NB, nb1 = 400 * NB, nb2 = 200 * NB;
        k1all<<<dim3(nb0 + nb1 + nb2), dim3(256), 0, stream>>>(
            ip, tp, xb0, xb1, xb2, NB, nb0, nb1);
        // k23 rows: s2 first, then s1, then s0
        const int r2 = NB * 9 * 9, r1 = NB * 25 * 25, r0 = NB * 71 * 71;
        k23all<<<dim3(r2 + r1 + r0), dim3(256), 0, stream>>>(
            xb0, xb1, xb2, acc, NB, r2, r1);
    }
    finalize_kernel<<<dim3(1), dim3(64), 0, stream>>>(
        acc, out,
        2.f * 71.f * 71.f * 71.f,
        2.f * 25.f * 25.f * 25.f,
        2.f * 9.f * 9.f * 9.f,
        0.1f, 0.3f, 0.6f);
}

// Round 7
// 166.788 us; speedup vs baseline: 1.7893x; 1.7818x over previous
//
#include <hip/hip_runtime.h>

#define DD 160

// ============ K1 body: x-pass sliding window (one scale) ============
// in/tg raw [B][160][160][160] -> xb 5 channels [ch][b][x'][y][z].
// NCH parity chains (2 for odd S); slide step NCH*S even -> remove/add R taps.
// All tap loads batched into static arrays to force outstanding loads.
template<int N, int K, int S, int NCH, int CL>
__device__ __forceinline__ void k1_body(
    const float* __restrict__ in, const float* __restrict__ tg,
    float* __restrict__ xb, int B, long t) {
    const long XS = (long)DD * DD;
    const long P  = (long)B * XS;
    constexpr int NPC0 = (N + NCH - 1) / NCH;
    constexpr int CC   = (NPC0 + CL - 1) / CL;
    constexpr int R    = (NCH * S) / 2;
    if (t >= P * NCH * CC) return;
    long p = t % P;
    int  r = (int)(t / P);
    int chain  = r % NCH;
    int cchunk = r / NCH;
    int b = (int)(p / XS);
    long yz = p % XS;
    const float* ia = in + (long)b * DD * XS + yz;
    const float* ta = tg + (long)b * DD * XS + yz;
    const long CH = (long)B * N * XS;
    float* ob = xb + (long)b * N * XS + yz;

    const int npc = (N - chain + NCH - 1) / NCH;
    int j0 = cchunk * CL;
    if (j0 >= npc) return;
    int xp = chain + j0 * NCH;
    int x0 = xp * S;
    float s0 = 0.f, s1 = 0.f, s2 = 0.f, s3 = 0.f, s4 = 0.f;

    constexpr int G = (K >= 16) ? 8 : K;
#pragma unroll
    for (int g = 0; g < K; g += G) {
        float u[G], w[G];
#pragma unroll
        for (int j = 0; j < G; ++j)
            if (g + j < K) {
                u[j] = ia[(long)(x0 + 2 * (g + j)) * XS];
                w[j] = ta[(long)(x0 + 2 * (g + j)) * XS];
            }
#pragma unroll
        for (int j = 0; j < G; ++j)
            if (g + j < K) {
                s0 += u[j]; s1 += w[j]; s2 += u[j] * u[j];
                s3 += w[j] * w[j]; s4 += u[j] * w[j];
            }
    }
    {
        long oo = (long)xp * XS;
        ob[oo] = s0; ob[oo + CH] = s1; ob[oo + 2 * CH] = s2;
        ob[oo + 3 * CH] = s3; ob[oo + 4 * CH] = s4;
    }
#pragma unroll
    for (int q = 1; q < CL; ++q) {
        if (j0 + q >= npc) break;
        float ru[R], rw[R], au[R], aw[R];
#pragma unroll
        for (int j = 0; j < R; ++j) {
            ru[j] = ia[(long)(x0 + 2 * j) * XS];
            rw[j] = ta[(long)(x0 + 2 * j) * XS];
            au[j] = ia[(long)(x0 + 2 * K + 2 * j) * XS];
            aw[j] = ta[(long)(x0 + 2 * K + 2 * j) * XS];
        }
#pragma unroll
        for (int j = 0; j < R; ++j) {
            s0 += au[j] - ru[j];
            s1 += aw[j] - rw[j];
            s2 += au[j] * au[j] - ru[j] * ru[j];
            s3 += aw[j] * aw[j] - rw[j] * rw[j];
            s4 += au[j] * aw[j] - ru[j] * rw[j];
        }
        xp += NCH;
        x0 += NCH * S;
        long oo = (long)xp * XS;
        ob[oo] = s0; ob[oo + CH] = s1; ob[oo + 2 * CH] = s2;
        ob[oo + 3 * CH] = s3; ob[oo + 4 * CH] = s4;
    }
}

// All three scales, one dispatch. s2/s1 (long-serial threads) first.
__global__ __launch_bounds__(256) void k1all(
    const float* __restrict__ in, const float* __restrict__ tg,
    float* __restrict__ xb0, float* __restrict__ xb1, float* __restrict__ xb2,
    int B, int nb2, int nb1) {
    int bid = blockIdx.x;
    if (bid < nb2) {
        k1_body<9, 40, 10, 1, 5>(in, tg, xb2, B, (long)bid * 256 + threadIdx.x);
    } else if (bid < nb2 + nb1) {
        k1_body<25, 20, 5, 2, 7>(in, tg, xb1, B, (long)(bid - nb2) * 256 + threadIdx.x);
    } else {
        k1_body<71, 10, 2, 1, 12>(in, tg, xb0, B,
                                  (long)(bid - nb2 - nb1) * 256 + threadIdx.x);
    }
}

// ============ K23 body: fused y-window + z-scan + LNCC ============
// ONE WAVE per output row (b,x',y'); per channel: batched tap-column loads
// (branchless tail via dummy in-bounds load), parity prefix scan along z,
// window-diff -> LNCC -> wave reduce.
template<int N, int K, int S>
__device__ __forceinline__ void k23_body(
    const float* __restrict__ xb, float* __restrict__ acc, int B, long row,
    float* Sw, float* wsum) {
    constexpr float numel = (float)K * K * K;
    const int tid = threadIdx.x, wid = tid >> 6, lane = tid & 63;
    const long XS = (long)DD * DD;
    const long CH = (long)B * N * XS;
    const long R3 = (long)B * N * N;
    float v = 0.f;
    if (row < R3) {
        int yp = (int)(row % N); long rr = row / N;
        int xp = (int)(rr % N);
        int b  = (int)(rr / N);
        const float* base = xb + ((long)b * N + xp) * XS + (long)(yp * S) * DD;
        const int lane2 = (lane < 32) ? lane + 128 : lane + 64;  // dummy in-bounds
#pragma unroll
        for (int ch = 0; ch < 5; ++ch) {
            const float* cp = base + (long)ch * CH;
            float w0 = 0.f, w1 = 0.f, w2 = 0.f;
            constexpr int G = (K > 10) ? 10 : K;
#pragma unroll
            for (int g = 0; g < K; g += G) {
                float t0[G], t1[G], t2[G];
#pragma unroll
                for (int j = 0; j < G; ++j)
                    if (g + j < K) {
                        const float* pp = cp + (long)(2 * (g + j)) * DD;
                        t0[j] = pp[lane];
                        t1[j] = pp[lane + 64];
                        t2[j] = pp[lane2];
                    }
#pragma unroll
                for (int j = 0; j < G; ++j)
                    if (g + j < K) { w0 += t0[j]; w1 += t1[j]; w2 += t2[j]; }
            }
            w2 = (lane < 32) ? w2 : 0.f;
#pragma unroll
            for (int o = 2; o <= 32; o <<= 1) {
                float q0 = __shfl_up(w0, o);
                float q1 = __shfl_up(w1, o);
                float q2 = __shfl_up(w2, o);
                if (lane >= o) { w0 += q0; w1 += q1; w2 += q2; }
            }
            float c1 = __shfl(w0, 62 + (lane & 1)); w1 += c1;
            float c2 = __shfl(w1, 62 + (lane & 1)); w2 += c2;
            float* outp = Sw + ch * 162;
            if (lane < 2) outp[lane] = 0.f;
            outp[lane + 2]  = w0;
            outp[lane + 66] = w1;
            if (lane < 32) outp[lane + 130] = w2;
        }
#pragma unroll
        for (int t = lane; t < N; t += 64) {
            int lo = t * S, hi = lo + 2 * K;
            float a0 = Sw[0 * 162 + hi] - Sw[0 * 162 + lo];
            float a1 = Sw[1 * 162 + hi] - Sw[1 * 162 + lo];
            float a2 = Sw[2 * 162 + hi] - Sw[2 * 162 + lo];
            float a3 = Sw[3 * 162 + hi] - Sw[3 * 162 + lo];
            float a4 = Sw[4 * 162 + hi] - Sw[4 * 162 + lo];
            float xm = a0 / numel, ym = a1 / numel;
            float cross = a4 - ym * a0 - xm * a1 + ym * xm * numel;
            float xvar  = a2 - 2.f * xm * a0 + xm * xm * numel;
            float yvar  = a3 - 2.f * ym * a1 + ym * ym * numel;
            v += cross * cross / (xvar * yvar + 1e-5f);
        }
    }
    for (int o = 32; o > 0; o >>= 1) v += __shfl_down(v, o, 64);
    if (lane == 0) wsum[wid] = v;
    __syncthreads();
    if (tid == 0) atomicAdd(acc, wsum[0] + wsum[1] + wsum[2] + wsum[3]);
}

// Segments: s2 [0,b2), s1 [b2,b2+b1), s0 rest (XCD-swizzled, bijective).
__global__ __launch_bounds__(256) void k23all(
    const float* __restrict__ xb0, const float* __restrict__ xb1,
    const float* __restrict__ xb2, float* __restrict__ acc,
    int B, int b2, int b1, int b0) {
    __shared__ float Sm[4][5][162];
    __shared__ float wsum[4];
    const int wid = threadIdx.x >> 6;
    float* Sw = &Sm[wid][0][0];
    int bid = blockIdx.x;
    if (bid < b2) {
        k23_body<9, 40, 10>(xb2, acc + 2, B, (long)bid * 4 + wid, Sw, wsum);
    } else if (bid < b2 + b1) {
        k23_body<25, 20, 5>(xb1, acc + 1, B, (long)(bid - b2) * 4 + wid, Sw, wsum);
    } else {
        int local = bid - b2 - b1;
        int q = b0 >> 3, r8 = b0 & 7;
        int xcd = local & 7, idx = local >> 3;
        int swz = (xcd < r8) ? xcd * (q + 1) + idx
                             : r8 * (q + 1) + (xcd - r8) * q + idx;
        k23_body<71, 10, 2>(xb0, acc + 0, B, (long)swz * 4 + wid, Sw, wsum);
    }
}

__global__ void finalize_kernel(const float* __restrict__ acc, float* __restrict__ out,
                                float c0, float c1, float c2,
                                float w0, float w1, float w2) {
    if (threadIdx.x == 0 && blockIdx.x == 0) {
        out[0] = w0 * (1.f - acc[0] / c0) +
                 w1 * (1.f - acc[1] / c1) +
                 w2 * (1.f - acc[2] / c2);
    }
}

extern "C" void kernel_launch(void* const* d_in, const int* in_sizes, int n_in,
                              void* d_out, int out_size, void* d_ws, size_t ws_size,
                              hipStream_t stream) {
    const float* input  = (const float*)d_in[0];
    const float* target = (const float*)d_in[1];
    float* out = (float*)d_out;

    char* ws = (char*)d_ws;
    float* acc = (float*)ws;
    const size_t accPad = 256;
    const long XS = (long)DD * DD;

    // full-batch (NB=2) need: 5*2*(71+25+9)*25600 floats = ~107.5 MB
    const size_t fullNeed = accPad + 5ull * 2 * 105 * XS * sizeof(float);
    const int NB = (ws_size >= fullNeed) ? 2 : 1;

    float* xb0 = (float*)(ws + accPad);
    float* xb1 = xb0 + 5ull * NB * 71 * XS;
    float* xb2 = xb1 + 5ull * NB * 25 * XS;

    hipMemsetAsync(acc, 0, 3 * sizeof(float), stream);

    for (int b0i = 0; b0i < 2; b0i += NB) {
        const float* ip = input  + (size_t)b0i * DD * XS;
        const float* tp = target + (size_t)b0i * DD * XS;
        // k1 blocks per scale: s0 600*NB (CC=6), s1 400*NB (NCH*CC=4), s2 200*NB (CC=2)
        const int nb0 = 600 * NB, nb1 = 400 * NB, nb2 = 200 * NB;
        k1all<<<dim3(nb2 + nb1 + nb0), dim3(256), 0, stream>>>(
            ip, tp, xb0, xb1, xb2, NB, nb2, nb1);
        // k23 blocks (4 rows/block): s2, s1 first; s0 ocean swizzled
        const int b2 = (NB * 81 + 3) / 4, b1 = (NB * 625 + 3) / 4,
                  b0 = (NB * 71 * 71 + 3) / 4;
        k23all<<<dim3(b2 + b1 + b0), dim3(256), 0, stream>>>(
            xb0, xb1, xb2, acc, NB, b2, b1, b0);
    }
    finalize_kernel<<<dim3(1), dim3(64), 0, stream>>>(
        acc, out,
        2.f * 71.f * 71.f * 71.f,
        2.f * 25.f * 25.f * 25.f,
        2.f * 9.f * 9.f * 9.f,
        0.1f, 0.3f, 0.6f);
}